// Round 13
// baseline (1679.658 us; speedup 1.0000x reference)
//
#include <hip/hip_runtime.h>

#define BT   (512*256)
#define HB0b 128   // hbuf (bytes): zeros @0..127, h @128..255

using short8  = __attribute__((ext_vector_type(8))) short;
using floatx4 = __attribute__((ext_vector_type(4))) float;
using int4v   = __attribute__((ext_vector_type(4))) int;

__device__ inline unsigned short f2bf(float f){
  unsigned int u = __float_as_uint(f);
  u += 0x7FFFu + ((u >> 16) & 1u);          // RNE
  return (unsigned short)(u >> 16);
}
__device__ inline float bf2f(unsigned short u){
  return __uint_as_float(((unsigned int)u) << 16);
}
__device__ inline float rcpf(float x){ return __builtin_amdgcn_rcpf(x); }

// 256 blocks x 512 threads = 2 DECOUPLED groups x 4 waves; group g owns batch
// 2bb+g, syncs on its own LDS counter (GSYNC, round-7-verified) -- no
// __syncthreads in the loop.  Each SIMD holds one wave of each group; groups
// drift anti-phase so one group's MFMA bursts fill the other's serial stalls.
// HARD CONSTRAINT (5 data points): 512-thread blocks cap at 128 VGPRs, so
// ONLY W_hh-i8 fragments (wq, 64 regs) are register-resident; W_ih (bf16),
// fc1 (i8), biases live in LDS tables read transiently per phase.  Gate
// MFMAs chained, hh-halves sequential: transient live-set ~16 regs.
// i8 quant as rounds 10/11 (verified): h q127, W per-row scale, i32 exact.
__global__ __launch_bounds__(512,1) void k_seq(
    const float* __restrict__ in,
    const float* __restrict__ Wih,  const float* __restrict__ Whh,
    const float* __restrict__ bih,  const float* __restrict__ bhh,
    const float* __restrict__ fc1w, const float* __restrict__ fc1b,
    const float* __restrict__ fc2w, const float* __restrict__ fc2b,
    const float* __restrict__ i1w,  const float* __restrict__ i1b,
    const float* __restrict__ i3w,  const float* __restrict__ i3b,
    const float* __restrict__ scw,  const float* __restrict__ zonew,
    float* __restrict__ out)
{
  __shared__ __align__(16) signed char hbuf[2][2][256];    // [g][buf] 1 KB
  __shared__ __align__(16) unsigned short xg[2][4096];     // [g][k][u][gate] bf16 16 KB (+init scratch)
  __shared__ __align__(16) unsigned short wihl[512*8];     // bf16 W_ih rows padded  8 KB
  __shared__ __align__(16) signed char fc1q[128*128];      // i8 fc1 row-major      16 KB
  __shared__ float dqf_l[128];                             // fc1 rowmax
  __shared__ float bsum_l[512];                            // bih+bhh               2 KB
  __shared__ __align__(8)  unsigned short toutl[2][256];
  __shared__ __align__(8)  unsigned short extl[2][256];
  __shared__ __align__(16) unsigned short exl[2][1024];    // bf16 Ext_X cols [t][4] 4 KB
  __shared__ float t0l[2][256];
  __shared__ float hvitl[2][256];
  __shared__ float parts[2][4];
  __shared__ unsigned int ctr[32];

  const int tid = threadIdx.x;
  const int g   = tid >> 8;             // group 0/1  (= batch 2bb+g)
  const int t   = tid & 255;            // group-local tid
  const int wvg = (tid >> 6) & 3;       // group-local wave 0..3
  const int ln  = tid & 63;
  const int l15 = ln & 15;
  const int quad= ln >> 4;
  const int bb  = blockIdx.x;
  const int gb  = 2*bb + g;             // this group's batch

  // ---- init pass 1: tables ----
  {
    const float* row = in + gb*1792 + t*7;
    t0l[g][t] = row[0];
    exl[g][t*4+0]=f2bf(row[1]); exl[g][t*4+1]=f2bf(row[2]);
    exl[g][t*4+2]=f2bf(row[3]); exl[g][t*4+3]=f2bf(row[4]);
  }
  hbuf[g][0][t] = 0;
  hbuf[g][1][t] = 0;
  if(t<8) toutl[g][t] = f2bf(in[gb*1792 + t*7]);
  if(t==0) ctr[g*16] = 0;
  {  // W_ih bf16 rows padded to 8 (one row per thread)
    #pragma unroll
    for(int c=0;c<8;c++) wihl[tid*8+c] = (c<5)? f2bf(Wih[tid*5+c]) : (unsigned short)0;
  }
  bsum_l[tid] = bih[tid] + bhh[tid];
  if(tid<128){  // fc1 rowmax
    const float* fr = fc1w + tid*128;
    float mx = 1e-20f;
    for(int j=0;j<128;j++) mx = fmaxf(mx, fabsf(fr[j]));
    dqf_l[tid] = mx;
  }
  float* lw4 = (float*)&xg[1][0];       // int-module scratch (retired pre-loop)
  float* l3  = lw4 + 512;
  if(tid<128){
    lw4[tid*4+0]=i1w[tid*3+0]; lw4[tid*4+1]=i1w[tid*3+1];
    lw4[tid*4+2]=i1w[tid*3+2]; lw4[tid*4+3]=i1b[tid];
    l3[tid]=i3w[tid];
  }
  __syncthreads();
  if(t<128) hbuf[g][0][HB0b + t] = 127;       // h = 1.0 -> q = 127
  {  // fc1 i8 pack: 32 bytes per thread
    for(int idx=tid*32; idx<tid*32+32; idx++){
      int r = idx>>7, c2 = idx&127;
      float qs = 127.f * rcpf(dqf_l[r]);
      int q = __float2int_rn(fc1w[r*128+c2]*qs);
      fc1q[idx] = (signed char)q;
    }
  }

  // ---- fused int module ----
  {
    const float b30=i3b[0], sc0=scw[0];
    const float* row = in + gb*1792 + t*7;
    float x0=row[3],x1=row[4],x2=row[5], acc=0.f;
    #pragma unroll 8
    for(int j=0;j<128;j++){
      float r=fmaxf(lw4[j*4]*x0+lw4[j*4+1]*x1+lw4[j*4+2]*x2+lw4[j*4+3],0.f);
      acc += r*l3[j];
    }
    float v = rcpf(1.f+__expf(-(acc+b30)))*sc0;
    float itv = (t<8)?0.f:v;
    hvitl[g][t] = row[6] + itv;
    out[3*BT+gb*256+t]=itv;              // Int_list
    out[BT+gb*256+t]=row[6];             // HVAC_list
    if(t<8){ out[gb*256+t]=row[0]; out[2*BT+gb*256+t]=0.f; }
  }

  // ---- W_hh i8 (ONLY register-resident weights): wave wvg = units 32wvg..+31 ----
  int4v wq[4][2][2];     // [gate][hh][Kchunk]  = 64 VGPRs
  float dq4[4];          // dequant for lane's own hh half only
  const int hi = quad & 1;
  #pragma unroll
  for(int gg=0;gg<4;gg++){
    #pragma unroll
    for(int hh=0;hh<2;hh++){
      int n = 128*gg + 32*wvg + 16*hh + l15;
      const float* wr = Whh + n*128;
      float mx = 1e-20f;
      for(int j=0;j<128;j++) mx = fmaxf(mx, fabsf(wr[j]));
      float qs = 127.f/mx;
      if(hh==hi) dq4[gg] = mx * (1.f/16129.f);   // 1/127^2
      #pragma unroll
      for(int c=0;c<2;c++){
        int4v v4;
        #pragma unroll
        for(int d=0;d<4;d++){
          int pk=0;
          #pragma unroll
          for(int bq=0;bq<4;bq++){
            int kk = c*64 + quad*16 + d*4 + bq;
            int q = __float2int_rn(wr[kk]*qs);
            pk |= (q & 255) << (8*bq);
          }
          v4[d]=pk;
        }
        wq[gg][hh][c]=v4;
      }
    }
  }

  // ---- per-lane persistent scalars ----
  const int  u2    = 32*wvg + 16*hi + l15;  // this lane's unit (quad>>1 dups)
  const int  aoff  = (((l15&3)==0) ? HB0b : 0) + quad*16;
  const int  hwoff = HB0b + u2;
  const float fb    = fc1b[u2];
  const float fcw_u = fc2w[u2];
  const float dqf_u = dqf_l[u2] * (1.f/16129.f);
  const float fc2b0 = fc2b[0];
  const float zwv   = zonew[0];
  const floatx4 ZV  = {0.f,0.f,0.f,0.f};
  const int4v   ZI  = {0,0,0,0};
  const short8  Z8  = 0;
  float E0 = in[gb*1792 + 56];              // E in EVERY lane's registers
  float c0 = 1.f;
  __syncthreads();                          // scratch/tables published; groups decouple now
  if(g==1){ __builtin_amdgcn_s_sleep(4); __builtin_amdgcn_s_sleep(4); }  // anti-phase stagger

  // ---- group-local sync (round-7-verified): LDS counter + s_sleep poll ----
  unsigned int tgt = 0;
  volatile unsigned int* vct = (volatile unsigned int*)&ctr[g*16];
  #define GSYNC() do{ tgt += 4;                                           \
      __builtin_amdgcn_s_waitcnt(0xc07f); asm volatile("" ::: "memory");  \
      if(ln==0) atomicAdd((unsigned int*)&ctr[g*16], 1u);                 \
      if(*vct < tgt){ do{ __builtin_amdgcn_s_sleep(1); }while(*vct < tgt);} \
      asm volatile("" ::: "memory"); }while(0)

  #pragma unroll 1
  for(int i=8;i<256;i++){
    // ===== phase A: deferred E-update (i-1), TOut, embed, x-MFMA (LDS B) =====
    if(i>8){
      float ext0 = parts[g][0]+parts[g][1]+parts[g][2]+parts[g][3] + fc2b0;
      int ip = i-1;
      float tot0 = ext0 + hvitl[g][ip];
      if(ip<128){
        float ratio=(float)ip*0.0078125f;
        E0 = ratio*t0l[g][ip] + (1.f-ratio)*E0 + tot0*zwv;
      } else {
        E0 += tot0*zwv;
      }
      if(t==0) extl[g][ip]=f2bf(ext0);
    }
    if(t==0) toutl[g][i]=f2bf(E0);          // TOut[:,i]=E
    {
      short8 ea = Z8;                       // A rows m = k (0..7), 8..15 zero
      if(quad==0 && l15<8){
        int p = i-7+l15;
        float tos = (l15==7) ? E0 : bf2f(toutl[g][p]);
        float tmix;
        if(i<128){
          float ratio=(float)i*0.0078125f;
          tmix = t0l[g][p]*ratio + tos*(1.f-ratio);
        } else tmix = tos;
        ea[0]=(short)f2bf(tmix);
        ea[1]=(short)exl[g][p*4+0]; ea[2]=(short)exl[g][p*4+1];
        ea[3]=(short)exl[g][p*4+2]; ea[4]=(short)exl[g][p*4+3];
      }
      #pragma unroll
      for(int gg=0;gg<4;gg++){
        #pragma unroll
        for(int hh=0;hh<2;hh++){
          int n = 128*gg + 32*wvg + 16*hh + l15;
          short8 xb = Z8;
          if(quad==0) xb = *(const short8*)&wihl[n*8];   // K elems 0..7 only
          floatx4 z=__builtin_amdgcn_mfma_f32_16x16x32_bf16(ea, xb, ZV,0,0,0);
          if(quad<2){
            float bs = bsum_l[n];
            #pragma unroll
            for(int r=0;r<4;r++){
              int k=4*quad+r;               // D row m = k
              xg[g][k*512 + (32*wvg+16*hh+l15)*4 + gg] = f2bf(z[r]+bs);
            }
          }
        }
      }
    }
    GSYNC();

    // ===== 8 inner LSTM steps: 16 chained i8 MFMAs/wave, 1 GSYNC each =====
    #pragma unroll
    for(int k=0;k<8;k++){
      const unsigned int* xp = (const unsigned int*)&xg[g][k*512 + u2*4];
      unsigned int xlo = xp[0], xhi = xp[1];
      float xv0 = __uint_as_float(xlo << 16);
      float xv1 = __uint_as_float(xlo & 0xffff0000u);
      float xv2 = __uint_as_float(xhi << 16);
      float xv3 = __uint_as_float(xhi & 0xffff0000u);
      const signed char* hb = &hbuf[g][k&1][0];
      int4v a0 = *(const int4v*)(hb + aoff);        // K 0..63
      int4v a1 = *(const int4v*)(hb + aoff + 64);   // K 64..127
      int isel[4];
      #pragma unroll
      for(int hh=0;hh<2;hh++){                      // sequential halves: low live-set
        #pragma unroll
        for(int gg=0;gg<4;gg++){
          int4v z = __builtin_amdgcn_mfma_i32_16x16x64_i8(a0, wq[gg][hh][0], ZI,0,0,0);
          z = __builtin_amdgcn_mfma_i32_16x16x64_i8(a1, wq[gg][hh][1], z,0,0,0);
          if(hh==0) isel[gg] = z[0];
          else      isel[gg] = hi ? z[0] : isel[gg];
        }
      }
      float gi = (float)isel[0]*dq4[0]+xv0;
      float gf = (float)isel[1]*dq4[1]+xv1;
      float gg2= (float)isel[2]*dq4[2]+xv2;
      float go = (float)isel[3]*dq4[3]+xv3;
      float ef =__expf(-gf);
      float egi=__expf(-gi);
      float egg=__expf(-2.f*gg2);
      float sf = rcpf(1.f+ef);
      float itn=(1.f-egg)*rcpf((1.f+egi)*(1.f+egg));
      c0 = sf*c0 + itn;
      float ego=__expf(-go);
      float ec =__expf(-2.f*c0);
      float hv2=(1.f-ec)*rcpf((1.f+ego)*(1.f+ec));
      if(quad<2){
        int q = __float2int_rn(hv2*127.f);          // |h|<1 -> |q|<=127
        hbuf[g][(k+1)&1][hwoff] = (signed char)q;
      }
      GSYNC();
    }

    // ===== fc1 (i8, B from LDS) + in-register fc2 partial reduce =====
    {
      const signed char* hb = &hbuf[g][0][0];
      int4v a0 = *(const int4v*)(hb + aoff);
      int4v a1 = *(const int4v*)(hb + aoff + 64);
      int isel = 0;
      #pragma unroll
      for(int hh=0;hh<2;hh++){
        int n2 = 32*wvg + 16*hh + l15;
        int4v b0 = *(const int4v*)&fc1q[n2*128 + quad*16];
        int4v b1 = *(const int4v*)&fc1q[n2*128 + 64 + quad*16];
        int4v z = __builtin_amdgcn_mfma_i32_16x16x64_i8(a0, b0, ZI,0,0,0);
        z = __builtin_amdgcn_mfma_i32_16x16x64_i8(a1, b1, z,0,0,0);
        if(hh==0) isel = z[0];
        else      isel = hi ? z[0] : isel;
      }
      float fv = (float)isel*dqf_u + fb;
      float pv = fmaxf(fv,0.f)*fcw_u;
      float v0 = (quad<2) ? pv : 0.f;               // quads 2,3 are dups
      #pragma unroll
      for(int off=32; off; off>>=1) v0 += __shfl_xor(v0, off, 64);
      if(ln==0) parts[g][wvg]=v0;
    }
    GSYNC();
  }

  // ===== tail: ext(255) =====
  if(t==0){
    float ext0 = parts[g][0]+parts[g][1]+parts[g][2]+parts[g][3] + fc2b0;
    extl[g][255]=f2bf(ext0);
  }
  GSYNC();

  // ===== flush TOut / Ext_list from LDS (group-local) =====
  for(int p=t; p<496; p+=256){
    int isT = (p < 248);
    int i2 = (isT ? p : p-248) + 8;
    if(isT) out[gb*256+i2]      = bf2f(toutl[g][i2]);
    else    out[2*BT+gb*256+i2] = bf2f(extl[g][i2]);
  }
  #undef GSYNC
}

extern "C" void kernel_launch(void* const* d_in, const int* in_sizes, int n_in,
                              void* d_out, int out_size, void* d_ws, size_t ws_size,
                              hipStream_t stream)
{
  const float* in   = (const float*)d_in[0];
  const float* Wih  = (const float*)d_in[1];
  const float* Whh  = (const float*)d_in[2];
  const float* bih  = (const float*)d_in[3];
  const float* bhh  = (const float*)d_in[4];
  const float* fc1w = (const float*)d_in[5];
  const float* fc1b = (const float*)d_in[6];
  const float* fc2w = (const float*)d_in[7];
  const float* fc2b = (const float*)d_in[8];
  const float* i1w  = (const float*)d_in[9];
  const float* i1b  = (const float*)d_in[10];
  const float* i3w  = (const float*)d_in[11];
  const float* i3b  = (const float*)d_in[12];
  const float* scw  = (const float*)d_in[13];
  const float* zw   = (const float*)d_in[14];
  float* out = (float*)d_out;

  k_seq<<<dim3(256), dim3(512), 0, stream>>>(in, Wih, Whh, bih, bhh,
                                             fc1w, fc1b, fc2w, fc2b,
                                             i1w, i1b, i3w, i3b, scw, zw, out);
}